// Round 4
// baseline (1477.263 us; speedup 1.0000x reference)
//
#include <hip/hip_runtime.h>
#include <hip/hip_bf16.h>

// Problem constants (from reference config)
#define CIN 256
#define COUT 256
#define HW 56
#define BATCH 8
#define L_SPATIAL 3136            // 56*56
#define K_TOTAL 2304              // CIN*3*3
#define NT 36                     // K_TOTAL / 64 chunks
#define KSTRIDE 2312              // bf16 elems per m-row in LDS (+8 pad)
#define ATILE_BYTES (16 * KSTRIDE * 2)       // 73,984 B
#define STAGE_FLOATS 2304                    // per-wave staging: 4m x 16c x 36n (one rg at a time)
#define TILES_PER_IMG 196                    // 3136/16 m-tiles per batch image
#define N_MTILES 1568
#define ASW_ELEMS_PER_TILE (NT * 2 * 512)    // 36,864 bf16 = 73,728 B per m-tile
#define QMAXF 127.0f
#define QMINF -128.0f

typedef short bf16x8 __attribute__((ext_vector_type(8)));
typedef float f32x4 __attribute__((ext_vector_type(4)));

__device__ __forceinline__ void nt_store4(float* p, f32x4 v) {
  __builtin_nontemporal_store(v, reinterpret_cast<f32x4*>(p));
}

// ---- prep: Bsign[c][k] = sign(w) as bf16 (B^T layout = MFMA B-frag order), scale[c] = mean|w| ----
__global__ __launch_bounds__(256) void prep_kernel(
    const float* __restrict__ w, unsigned short* __restrict__ bsign,
    float* __restrict__ scale) {
  const int c = blockIdx.x;
  const int t = threadIdx.x;
  const float* row = w + (size_t)c * K_TOTAL;
  unsigned short* out = bsign + (size_t)c * K_TOTAL;
  float acc = 0.0f;
#pragma unroll
  for (int j = 0; j < 9; ++j) {
    const int k = t + 256 * j;
    const float v = row[k];
    acc += __builtin_fabsf(v);
    out[k] = (v > 0.0f) ? (unsigned short)0x3F80
           : ((v < 0.0f) ? (unsigned short)0xBF80 : (unsigned short)0);
  }
#pragma unroll
  for (int o = 32; o > 0; o >>= 1) acc += __shfl_down(acc, o, 64);
  __shared__ float red[4];
  if ((t & 63) == 0) red[t >> 6] = acc;
  __syncthreads();
  if (t == 0) scale[c] = (red[0] + red[1] + red[2] + red[3]) * (1.0f / 2304.0f);
}

// ================= split path =================
// K1: im2col, output in MFMA A-frag order: [mtile][n][frag][lane][8 bf16]
__global__ __launch_bounds__(256) void im2col_kernel(
    const float* __restrict__ x, unsigned short* __restrict__ asw) {
  extern __shared__ unsigned short Atile[];   // [16][KSTRIDE]
  const int tid = threadIdx.x;
  const int m_tile = blockIdx.x;
  const int m0 = m_tile << 4;
  {
    const int ml = tid & 15;
    const int grp = tid >> 4;                 // 0..15
    const int m = m0 + ml;
    const int b = m / L_SPATIAL;
    const int l = m - b * L_SPATIAL;
    const int oh = l / HW;
    const int ow = l - oh * HW;
    const float* xb = x + (size_t)b * (CIN * L_SPATIAL);
    unsigned short* arow = Atile + ml * KSTRIDE;
    for (int r = grp; r < 768; r += 16) {     // r = ci*3 + kh
      const int ci = r / 3;
      const int kh = r - ci * 3;
      const int h = oh + kh - 1;
      const bool hv = ((unsigned)h < (unsigned)HW);
      const float* xr = xb + (ci * HW + h) * HW;
      const int kb = ci * 9 + kh * 3;
#pragma unroll
      for (int kw = 0; kw < 3; ++kw) {
        const int wv = ow + kw - 1;
        float v = 0.0f;
        if (hv && ((unsigned)wv < (unsigned)HW)) v = xr[wv];
        __hip_bfloat16 bv = __float2bfloat16(v);
        arow[kb + kw] = *reinterpret_cast<unsigned short*>(&bv);
      }
    }
  }
  __syncthreads();
  unsigned short* dst = asw + (size_t)m_tile * ASW_ELEMS_PER_TILE;
#pragma unroll
  for (int it = 0; it < 18; ++it) {
    const int flat = it * 256 + tid;          // unit = 8 bf16 (16 B)
    const int n = flat >> 7;                  // 128 units per n
    const int rem = flat & 127;
    const int frag = rem >> 6;
    const int ln = rem & 63;
    const int cl = ln & 15;
    const int q = ln >> 4;
    bf16x8 v = *reinterpret_cast<const bf16x8*>(
        Atile + cl * KSTRIDE + n * 64 + frag * 32 + q * 8);
    *reinterpret_cast<bf16x8*>(dst + (size_t)flat * 8) = v;   // contiguous 1KB/wave
  }
}

// K2: barrier-free GEMM + saturating scan + staged coalesced NT stores.
// 256 thr = 4 waves; wave owns 16m x 64c (4 subtiles of 16c).
__global__ __launch_bounds__(256, 2) void gemm_kernel(
    const unsigned short* __restrict__ asw, const unsigned short* __restrict__ bsign,
    const float* __restrict__ scale, float* __restrict__ y_out,
    float* __restrict__ psum_out) {
  __shared__ float stage_all[4 * STAGE_FLOATS];   // 36,864 B -> 2 WG/CU (VGPR-limited)
  const int tid = threadIdx.x;
  // XCD swizzle: each XCD owns one batch image (bsign + A-tiles hot in its L2)
  const int m_tile = (blockIdx.x & 7) * TILES_PER_IMG + (blockIdx.x >> 3);
  const int m0 = m_tile << 4;
  const int lane = tid & 63;
  const int wave = tid >> 6;                  // 0..3
  const int cl = lane & 15;
  const int q = lane >> 4;
  const int c0 = wave << 6;                   // 64 couts per wave
  float* stage = stage_all + wave * STAGE_FLOATS;   // wave-private, DS in-order

  const unsigned short* atile =
      asw + (size_t)m_tile * ASW_ELEMS_PER_TILE + lane * 8;
  const int b_img = m0 / L_SPATIAL;
  const int l0 = m0 - b_img * L_SPATIAL;

  int base_it[9];
#pragma unroll
  for (int it = 0; it < 9; ++it) {
    const int f = it * 256 + lane * 4;
    const int qq = f / 576;
    const int rem = f - qq * 576;
    const int ci = rem / 36;
    const int n0 = rem - ci * 36;
    base_it[it] = ((m0 + (qq << 2)) * COUT + ci) * NT + n0;
  }

  for (int s = 0; s < 4; ++s) {
    const int csub0 = c0 + (s << 4);
    const int c = csub0 + cl;
    const float sc = scale[c];
    const unsigned short* bptr = bsign + (size_t)c * K_TOTAL + q * 8;
    f32x4 ps[NT];
    f32x4 sacc = {0.0f, 0.0f, 0.0f, 0.0f};
    const f32x4 zero = {0.0f, 0.0f, 0.0f, 0.0f};
#pragma unroll
    for (int n = 0; n < NT; ++n) {
      bf16x8 a0 = *reinterpret_cast<const bf16x8*>(atile + n * 1024);
      bf16x8 a1 = *reinterpret_cast<const bf16x8*>(atile + n * 1024 + 512);
      bf16x8 b0 = *reinterpret_cast<const bf16x8*>(bptr + n * 64);
      bf16x8 b1 = *reinterpret_cast<const bf16x8*>(bptr + n * 64 + 32);
      f32x4 acc = __builtin_amdgcn_mfma_f32_16x16x32_bf16(a0, b0, zero, 0, 0, 0);
      acc = __builtin_amdgcn_mfma_f32_16x16x32_bf16(a1, b1, acc, 0, 0, 0);
      ps[n] = acc;
      if (n == 0) {
        sacc = acc;                           // scan carry starts UNCLIPPED (matches ref)
      } else {
#pragma unroll
        for (int e = 0; e < 4; ++e) {
          const float t = sacc[e] + acc[e];
          sacc[e] = __builtin_amdgcn_fmed3f(t, QMINF, QMAXF);
        }
      }
    }

    // ---- y: stage 16c x 16m block, full-line NT stores ----
    {
      f32x4 yv;
#pragma unroll
      for (int e = 0; e < 4; ++e) yv[e] = sacc[e] * sc;
      *reinterpret_cast<f32x4*>(stage + cl * 16 + q * 4) = yv;   // [c][m']
      const int ci = lane >> 2;
      const int mi = (lane & 3) << 2;
      f32x4 v = *reinterpret_cast<const f32x4*>(stage + lane * 4);
      nt_store4(y_out + ((size_t)b_img * COUT + (csub0 + ci)) * L_SPATIAL + l0 + mi, v);
    }

    // ---- psum: per-rg LDS transpose -> dense 64B-aligned 2304B bursts ----
    const int soff = csub0 * NT;
#pragma unroll
    for (int rg = 0; rg < 4; ++rg) {
#pragma unroll
      for (int g = 0; g < 9; ++g) {
        f32x4 v = {ps[4 * g + 0][rg], ps[4 * g + 1][rg],
                   ps[4 * g + 2][rg], ps[4 * g + 3][rg]};
        *reinterpret_cast<f32x4*>(stage + q * 576 + cl * 36 + 4 * g) = v;
      }
      const int rgoff = rg * (COUT * NT) + soff;
#pragma unroll
      for (int it = 0; it < 9; ++it) {
        f32x4 v = *reinterpret_cast<const f32x4*>(stage + it * 256 + lane * 4);
        nt_store4(psum_out + (size_t)(base_it[it] + rgoff), v);
      }
    }
  }
}

// ================= fallback (round-3 monolithic, proven) =================
#define FB_LDS_BYTES (ATILE_BYTES + 8 * STAGE_FLOATS * 4)  // 147,712 B
__global__ __launch_bounds__(512, 1) void satconv_kernel(
    const float* __restrict__ x, const unsigned short* __restrict__ bsign,
    const float* __restrict__ scale, float* __restrict__ y_out,
    float* __restrict__ psum_out) {
  extern __shared__ char smem[];
  unsigned short* Atile = (unsigned short*)smem;
  float* stage_base = (float*)(smem + ATILE_BYTES);
  const int tid = threadIdx.x;
  const int m_tile = (blockIdx.x & 7) * TILES_PER_IMG + (blockIdx.x >> 3);
  const int m0 = m_tile << 4;
  {
    const int ml = tid & 15;
    const int grp = tid >> 4;
    const int m = m0 + ml;
    const int b = m / L_SPATIAL;
    const int l = m - b * L_SPATIAL;
    const int oh = l / HW;
    const int ow = l - oh * HW;
    const float* xb = x + (size_t)b * (CIN * L_SPATIAL);
    unsigned short* arow = Atile + ml * KSTRIDE;
    for (int r = grp; r < 768; r += 32) {
      const int ci = r / 3;
      const int kh = r - ci * 3;
      const int h = oh + kh - 1;
      const bool hv = ((unsigned)h < (unsigned)HW);
      const float* xr = xb + (ci * HW + h) * HW;
      const int kb = ci * 9 + kh * 3;
#pragma unroll
      for (int kw = 0; kw < 3; ++kw) {
        const int wv = ow + kw - 1;
        float v = 0.0f;
        if (hv && ((unsigned)wv < (unsigned)HW)) v = xr[wv];
        __hip_bfloat16 bv = __float2bfloat16(v);
        arow[kb + kw] = *reinterpret_cast<unsigned short*>(&bv);
      }
    }
  }
  const int lane = tid & 63;
  const int wave = tid >> 6;
  const int cl = lane & 15;
  const int q = lane >> 4;
  const int c0 = wave << 5;
  float* stage = stage_base + wave * STAGE_FLOATS;
  const float sc_s0 = scale[c0 + cl];
  const float sc_s1 = scale[c0 + 16 + cl];
  int base_it[9];
#pragma unroll
  for (int it = 0; it < 9; ++it) {
    const int f = it * 256 + lane * 4;
    const int qq = f / 576;
    const int rem = f - qq * 576;
    const int ci = rem / 36;
    const int n0 = rem - ci * 36;
    base_it[it] = ((m0 + (qq << 2)) * COUT + ci) * NT + n0;
  }
  __syncthreads();
  const unsigned short* aptr = Atile + cl * KSTRIDE + q * 8;
  const int b_img = m0 / L_SPATIAL;
  const int l0 = m0 - b_img * L_SPATIAL;
  for (int s = 0; s < 2; ++s) {
    const int csub0 = c0 + (s << 4);
    const int c = csub0 + cl;
    const unsigned short* bptr = bsign + (size_t)c * K_TOTAL + q * 8;
    f32x4 ps[NT];
    f32x4 sacc = {0.0f, 0.0f, 0.0f, 0.0f};
    const f32x4 zero = {0.0f, 0.0f, 0.0f, 0.0f};
#pragma unroll
    for (int n = 0; n < NT; ++n) {
      bf16x8 a0 = *reinterpret_cast<const bf16x8*>(aptr + n * 64);
      bf16x8 a1 = *reinterpret_cast<const bf16x8*>(aptr + n * 64 + 32);
      bf16x8 b0 = *reinterpret_cast<const bf16x8*>(bptr + n * 64);
      bf16x8 b1 = *reinterpret_cast<const bf16x8*>(bptr + n * 64 + 32);
      f32x4 acc = __builtin_amdgcn_mfma_f32_16x16x32_bf16(a0, b0, zero, 0, 0, 0);
      acc = __builtin_amdgcn_mfma_f32_16x16x32_bf16(a1, b1, acc, 0, 0, 0);
      ps[n] = acc;
      if (n == 0) {
        sacc = acc;
      } else {
#pragma unroll
        for (int e = 0; e < 4; ++e) {
          const float t = sacc[e] + acc[e];
          sacc[e] = __builtin_amdgcn_fmed3f(t, QMINF, QMAXF);
        }
      }
    }
    {
      const float sc = (s == 0) ? sc_s0 : sc_s1;
      f32x4 yv;
#pragma unroll
      for (int e = 0; e < 4; ++e) yv[e] = sacc[e] * sc;
      *reinterpret_cast<f32x4*>(stage + cl * 16 + q * 4) = yv;
      const int ci = lane >> 2;
      const int mi = (lane & 3) << 2;
      f32x4 v = *reinterpret_cast<const f32x4*>(stage + lane * 4);
      nt_store4(y_out + ((size_t)b_img * COUT + (csub0 + ci)) * L_SPATIAL + l0 + mi, v);
    }
    const int soff = csub0 * NT;
#pragma unroll
    for (int rg = 0; rg < 4; ++rg) {
#pragma unroll
      for (int g = 0; g < 9; ++g) {
        f32x4 v = {ps[4 * g + 0][rg], ps[4 * g + 1][rg],
                   ps[4 * g + 2][rg], ps[4 * g + 3][rg]};
        *reinterpret_cast<f32x4*>(stage + q * 576 + cl * 36 + 4 * g) = v;
      }
      const int rgoff = rg * (COUT * NT) + soff;
#pragma unroll
      for (int it = 0; it < 9; ++it) {
        f32x4 v = *reinterpret_cast<const f32x4*>(stage + it * 256 + lane * 4);
        nt_store4(psum_out + (size_t)(base_it[it] + rgoff), v);
      }
    }
  }
}

extern "C" void kernel_launch(void* const* d_in, const int* in_sizes, int n_in,
                              void* d_out, int out_size, void* d_ws, size_t ws_size,
                              hipStream_t stream) {
  const float* x = (const float*)d_in[0];
  const float* w = (const float*)d_in[1];
  float* y = (float*)d_out;
  float* psum = y + (size_t)BATCH * COUT * L_SPATIAL;
  unsigned short* bsign = (unsigned short*)d_ws;                 // 1,179,648 B
  float* scale = (float*)((char*)d_ws + (size_t)COUT * K_TOTAL * 2);
  unsigned short* asw = (unsigned short*)((char*)d_ws + (2u << 20));  // @2MB
  const size_t need = (2u << 20) + (size_t)N_MTILES * ASW_ELEMS_PER_TILE * 2;

  prep_kernel<<<COUT, 256, 0, stream>>>(w, bsign, scale);

  if (ws_size >= need) {
    hipFuncSetAttribute(reinterpret_cast<const void*>(im2col_kernel),
                        hipFuncAttributeMaxDynamicSharedMemorySize, ATILE_BYTES);
    im2col_kernel<<<N_MTILES, 256, ATILE_BYTES, stream>>>(x, asw);
    gemm_kernel<<<N_MTILES, 256, 0, stream>>>(asw, bsign, scale, y, psum);
  } else {
    hipFuncSetAttribute(reinterpret_cast<const void*>(satconv_kernel),
                        hipFuncAttributeMaxDynamicSharedMemorySize, FB_LDS_BYTES);
    satconv_kernel<<<N_MTILES, 512, FB_LDS_BYTES, stream>>>(x, bsign, scale, y, psum);
  }
}

// Round 5
// 1200.729 us; speedup vs baseline: 1.2303x; 1.2303x over previous
//
#include <hip/hip_runtime.h>
#include <hip/hip_bf16.h>

// Problem constants (from reference config)
#define CIN 256
#define COUT 256
#define HW 56
#define BATCH 8
#define L_SPATIAL 3136            // 56*56
#define K_TOTAL 2304              // CIN*3*3
#define NT 36                     // K_TOTAL / 64 chunks
#define KSTRIDE 2312              // bf16 elems per m-row in LDS (+8 pad)
#define ATILE_BYTES (16 * KSTRIDE * 2)       // 73,984 B
#define STAGE_FLOATS 2304                    // per-wave staging: 4m x 16c x 36n (one rg at a time)
#define LDS_BYTES (ATILE_BYTES + 8 * STAGE_FLOATS * 4)  // 147,712 B -> 1 WG/CU, 8 waves
#define TILES_PER_IMG 196                    // 3136/16 m-tiles per batch image
#define QMAXF 127.0f
#define QMINF -128.0f

typedef short bf16x8 __attribute__((ext_vector_type(8)));
typedef float f32x4 __attribute__((ext_vector_type(4)));

// Plain full-line stores: the harness fill kernel proves dense dwordx4 streams
// write-combine in L2 with ZERO allocate-fetch at 6.25 TB/s. nt (round 3/4)
// correlated with 1.25 GB WRITE (1.3x inflation) -> removed.
__device__ __forceinline__ void st4(float* p, f32x4 v) {
  *reinterpret_cast<f32x4*>(p) = v;
}

// ---- prep: Bsign[c][k] = sign(w) as bf16 (B^T layout = MFMA B-frag order), scale[c] = mean|w| ----
__global__ __launch_bounds__(256) void prep_kernel(
    const float* __restrict__ w, unsigned short* __restrict__ bsign,
    float* __restrict__ scale) {
  const int c = blockIdx.x;
  const int t = threadIdx.x;
  const float* row = w + (size_t)c * K_TOTAL;
  unsigned short* out = bsign + (size_t)c * K_TOTAL;
  float acc = 0.0f;
#pragma unroll
  for (int j = 0; j < 9; ++j) {
    const int k = t + 256 * j;
    const float v = row[k];
    acc += __builtin_fabsf(v);
    out[k] = (v > 0.0f) ? (unsigned short)0x3F80
           : ((v < 0.0f) ? (unsigned short)0xBF80 : (unsigned short)0);
  }
#pragma unroll
  for (int o = 32; o > 0; o >>= 1) acc += __shfl_down(acc, o, 64);
  __shared__ float red[4];
  if ((t & 63) == 0) red[t >> 6] = acc;
  __syncthreads();
  if (t == 0) scale[c] = (red[0] + red[1] + red[2] + red[3]) * (1.0f / 2304.0f);
}

// ---- main: per WG = 16 m-rows x 256 cout (8 waves x 32c), LDS-staged coalesced output ----
__global__ __launch_bounds__(512, 1) void satconv_kernel(
    const float* __restrict__ x, const unsigned short* __restrict__ bsign,
    const float* __restrict__ scale, float* __restrict__ y_out,
    float* __restrict__ psum_out) {
  extern __shared__ char smem[];
  unsigned short* Atile = (unsigned short*)smem;               // [16][KSTRIDE] bf16
  float* stage_base = (float*)(smem + ATILE_BYTES);            // [8 waves][2304] f32

  const int tid = threadIdx.x;
  // XCD swizzle: 8 XCDs x 196 tiles; each XCD owns one batch image (x slice 3.2MB
  // + bsign 1.18MB fit its private 4MB L2).
  const int m_tile = (blockIdx.x & 7) * TILES_PER_IMG + (blockIdx.x >> 3);
  const int m0 = m_tile << 4;

  // ---------- build A tile: lanes 0-15 = consecutive m (= consecutive ow), coalesced x reads ----------
  {
    const int ml = tid & 15;
    const int grp = tid >> 4;                 // 0..31
    const int m = m0 + ml;
    const int b = m / L_SPATIAL;
    const int l = m - b * L_SPATIAL;
    const int oh = l / HW;
    const int ow = l - oh * HW;
    const float* xb = x + (size_t)b * (CIN * L_SPATIAL);
    unsigned short* arow = Atile + ml * KSTRIDE;
    for (int r = grp; r < 768; r += 32) {     // r = ci*3 + kh
      const int ci = r / 3;
      const int kh = r - ci * 3;
      const int h = oh + kh - 1;
      const bool hv = ((unsigned)h < (unsigned)HW);
      const float* xr = xb + (ci * HW + h) * HW;
      const int kb = ci * 9 + kh * 3;
#pragma unroll
      for (int kw = 0; kw < 3; ++kw) {
        const int wv = ow + kw - 1;
        float v = 0.0f;
        if (hv && ((unsigned)wv < (unsigned)HW)) v = xr[wv];
        __hip_bfloat16 bv = __float2bfloat16(v);
        arow[kb + kw] = *reinterpret_cast<unsigned short*>(&bv);
      }
    }
  }

  const int lane = tid & 63;
  const int wave = tid >> 6;                  // 0..7
  const int cl = lane & 15;
  const int q = lane >> 4;
  const int c0 = wave << 5;                   // 32 couts per wave
  float* stage = stage_base + wave * STAGE_FLOATS;   // private -> DS in-order per wave

  // hoist ALL scalar global loads before the store streams (keeps vmcnt clean)
  const float sc_s0 = scale[c0 + cl];
  const float sc_s1 = scale[c0 + 16 + cl];

  // precompute store-phase indices (lane+it dependent only; rg/s added later)
  int base_it[9];
  {
#pragma unroll
    for (int it = 0; it < 9; ++it) {
      const int f = it * 256 + lane * 4;
      const int qq = f / 576;
      const int rem = f - qq * 576;
      const int ci = rem / 36;
      const int n0 = rem - ci * 36;
      base_it[it] = ((m0 + (qq << 2)) * COUT + ci) * NT + n0;
    }
  }

  __syncthreads();

  const unsigned short* aptr = Atile + cl * KSTRIDE + q * 8;
  const int b_img = m0 / L_SPATIAL;           // WG never crosses batch boundary
  const int l0 = m0 - b_img * L_SPATIAL;

  for (int s = 0; s < 2; ++s) {               // 2 c-subtiles of 16 per wave
    const int csub0 = c0 + (s << 4);
    const int c = csub0 + cl;
    const unsigned short* bptr = bsign + (size_t)c * K_TOTAL + q * 8;
    f32x4 ps[NT];
    f32x4 sacc = {0.0f, 0.0f, 0.0f, 0.0f};
    const f32x4 zero = {0.0f, 0.0f, 0.0f, 0.0f};
    bf16x8 b0 = *reinterpret_cast<const bf16x8*>(bptr);
    bf16x8 b1 = *reinterpret_cast<const bf16x8*>(bptr + 32);
#pragma unroll
    for (int n = 0; n < NT; ++n) {
      bf16x8 nb0, nb1;
      if (n + 1 < NT) {                        // prefetch next B-frag
        nb0 = *reinterpret_cast<const bf16x8*>(bptr + (n + 1) * 64);
        nb1 = *reinterpret_cast<const bf16x8*>(bptr + (n + 1) * 64 + 32);
      }
      bf16x8 a0 = *reinterpret_cast<const bf16x8*>(aptr + n * 64);
      bf16x8 a1 = *reinterpret_cast<const bf16x8*>(aptr + n * 64 + 32);
      f32x4 acc = __builtin_amdgcn_mfma_f32_16x16x32_bf16(a0, b0, zero, 0, 0, 0);
      acc = __builtin_amdgcn_mfma_f32_16x16x32_bf16(a1, b1, acc, 0, 0, 0);
      ps[n] = acc;
      if (n == 0) {
        sacc = acc;                           // scan carry starts UNCLIPPED (matches ref)
      } else {
#pragma unroll
        for (int e = 0; e < 4; ++e) {
          const float t = sacc[e] + acc[e];
          sacc[e] = __builtin_amdgcn_fmed3f(t, QMINF, QMAXF);
        }
      }
      b0 = nb0;
      b1 = nb1;
    }

    // ---- y: stage 16c x 16m block, store full 64B lines ----
    {
      const float sc = (s == 0) ? sc_s0 : sc_s1;
      f32x4 yv;
#pragma unroll
      for (int e = 0; e < 4; ++e) yv[e] = sacc[e] * sc;
      *reinterpret_cast<f32x4*>(stage + cl * 16 + q * 4) = yv;   // [c][m'] layout
      const int ci = lane >> 2;
      const int mi = (lane & 3) << 2;
      f32x4 v = *reinterpret_cast<const f32x4*>(stage + lane * 4);
      st4(y_out + ((size_t)b_img * COUT + (csub0 + ci)) * L_SPATIAL + l0 + mi, v);
    }

    // ---- psum: per-rg LDS transpose -> dense 64B-aligned 2304B bursts ----
    const int soff = csub0 * NT;              // c-subtile offset in global
#pragma unroll
    for (int rg = 0; rg < 4; ++rg) {
#pragma unroll
      for (int g = 0; g < 9; ++g) {
        f32x4 v = {ps[4 * g + 0][rg], ps[4 * g + 1][rg],
                   ps[4 * g + 2][rg], ps[4 * g + 3][rg]};
        *reinterpret_cast<f32x4*>(stage + q * 576 + cl * 36 + 4 * g) = v;
      }
      const int rgoff = rg * (COUT * NT) + soff;
#pragma unroll
      for (int it = 0; it < 9; ++it) {
        f32x4 v = *reinterpret_cast<const f32x4*>(stage + it * 256 + lane * 4);
        st4(psum_out + (size_t)(base_it[it] + rgoff), v);
      }
    }
  }
}

extern "C" void kernel_launch(void* const* d_in, const int* in_sizes, int n_in,
                              void* d_out, int out_size, void* d_ws, size_t ws_size,
                              hipStream_t stream) {
  const float* x = (const float*)d_in[0];
  const float* w = (const float*)d_in[1];
  float* y = (float*)d_out;
  float* psum = y + (size_t)BATCH * COUT * L_SPATIAL;            // y is 6,422,528 floats
  unsigned short* bsign = (unsigned short*)d_ws;                 // 256*2304*2 = 1,179,648 B
  float* scale = (float*)((char*)d_ws + (size_t)COUT * K_TOTAL * 2);

  prep_kernel<<<COUT, 256, 0, stream>>>(w, bsign, scale);

  hipFuncSetAttribute(reinterpret_cast<const void*>(satconv_kernel),
                      hipFuncAttributeMaxDynamicSharedMemorySize, LDS_BYTES);
  satconv_kernel<<<(BATCH * L_SPATIAL) / 16, 512, LDS_BYTES, stream>>>(
      x, bsign, scale, y, psum);
}